// Round 10
// baseline (30.510 us; speedup 1.0000x reference)
//
#include <hip/hip_runtime.h>
#include <stdint.h>

#define K_DIM 4096
#define KW 1024          // packed words per m-row
#define M_DIM 11008
#define B_DIM 16
#define GROUP_ROWS 2752  // M / 4 groups
#define QTR_W 256
#define NTILES 688       // M / 16

typedef int v4i __attribute__((ext_vector_type(4)));

// spread low byte p (4x 2-bit fields) into 4 bytes: {p&3,(p>>2)&3,(p>>4)&3,(p>>6)&3}
__device__ __forceinline__ int spread2(int p) {
    int t = p | (p << 12);
    return (t & 0x00030003) | (((t >> 2) & 0x00030003) << 8);
}
__device__ __forceinline__ int dot4(int a, int b, int c) {
    return __builtin_amdgcn_sdot4(a, b, c, false);
}

// ---------------- kernel 1: per-row activation quantization ----------------
// 64 blocks x 256 thr: block g -> row b=g>>2, quarter qt=g&3. Full-row absmax
// (redundant, L2-hot), quantize own quarter. Partial sums to sumq_part[b][qt].
__global__ __launch_bounds__(256) void quant_k(const float* __restrict__ in,
                                               int* __restrict__ qg,
                                               int* __restrict__ sumq_part,
                                               float* __restrict__ invs) {
    const int g = blockIdx.x, b = g >> 2, qt = g & 3;
    const int t = threadIdx.x, lane = t & 63, wid = t >> 6;

    const float4* row = (const float4*)(in + (size_t)b * K_DIM);
    float4 v[4];
#pragma unroll
    for (int i = 0; i < 4; ++i) v[i] = row[t + i * 256];

    float mx = 0.f;
#pragma unroll
    for (int i = 0; i < 4; ++i) {
        mx = fmaxf(mx, fabsf(v[i].x)); mx = fmaxf(mx, fabsf(v[i].y));
        mx = fmaxf(mx, fabsf(v[i].z)); mx = fmaxf(mx, fabsf(v[i].w));
    }
#pragma unroll
    for (int s = 1; s < 64; s <<= 1) mx = fmaxf(mx, __shfl_xor(mx, s, 64));

    __shared__ float wmax[4];
    __shared__ int wsum[4];
    if (lane == 0) wmax[wid] = mx;
    __syncthreads();
    const float bm = fmaxf(fmaxf(wmax[0], wmax[1]), fmaxf(wmax[2], wmax[3]));
    const float sc = 127.f / fmaxf(bm, 1e-5f);

    const float4 mine = v[qt];  // thread t quantizes word qt*256 + t
    float xs[4] = {mine.x, mine.y, mine.z, mine.w};
    int w = 0, ss = 0;
#pragma unroll
    for (int j = 0; j < 4; ++j) {
        int q = (int)rintf(xs[j] * sc);   // round-half-even, matches jnp.round
        q = q > 127 ? 127 : (q < -128 ? -128 : q);
        ss += q;
        w |= (q & 255) << (8 * j);
    }
    qg[b * KW + qt * QTR_W + t] = w;

#pragma unroll
    for (int s = 1; s < 64; s <<= 1) ss += __shfl_xor(ss, s, 64);
    if (lane == 0) wsum[wid] = ss;
    __syncthreads();
    if (t == 0) {
        sumq_part[b * 4 + qt] = wsum[0] + wsum[1] + wsum[2] + wsum[3];
        if (qt == 0) invs[b] = fmaxf(bm, 1e-5f) / 127.f;
    }
}

// ---------------- kernel 2: streaming ternary GEMM via sdot4 ----------------
// 688 blocks x 256 thr (4 waves), ALL blocks co-resident (~3/CU). Wave wid owns
// k-words [wid*256,(wid+1)*256); lane owns 4 fixed words. Weights: one int4 per
// row, CONTIGUOUS 1 KB per wave-instruction (copy-identical pattern), 8-deep
// register pipeline (progressive vmcnt(7), never drains). Consumption is pure
// VALU (spread2 + sdot4) straight from load regs: no LDS, no MFMA, no staging
// interlocks. Per row: 17-op halving butterfly -> lanes 0..15 hold per-b sums.
__global__ __launch_bounds__(256, 3) void gemm_k(const int* __restrict__ wp,
                                                 const int* __restrict__ qg,
                                                 const int* __restrict__ sumq_part,
                                                 const float* __restrict__ invs,
                                                 const float* __restrict__ wscale,
                                                 float* __restrict__ out) {
    __shared__ int red[4][16][16];  // 4 KB
    const int t = threadIdx.x, lane = t & 63, wid = t >> 6;
    const int m0 = blockIdx.x * 16;
    const int kbase = wid * QTR_W + lane * 4;  // this thread's fixed k-word window

    // q: 16 int4 (one per batch row) for this thread's k-window; issued first
    // so they are oldest in the vmcnt queue (retired by the first vmcnt(7)).
    v4i qr[16];
#pragma unroll
    for (int b = 0; b < 16; ++b) qr[b] = *(const v4i*)(qg + b * KW + kbase);

    const int* wb = wp + (size_t)m0 * KW + kbase;

    // 8-deep weight pipeline: 8 x 1KB-per-wave contiguous loads in flight
    v4i wpipe[8];
#pragma unroll
    for (int j = 0; j < 8; ++j) wpipe[j] = *(const v4i*)(wb + (size_t)j * KW);

    // lane -> b index after the halving butterfly (bitrev4 of lane&15)
    const int a = ((lane & 1) << 3) | ((lane & 2) << 1) | ((lane & 4) >> 1) | ((lane & 8) >> 3);

    int acc2[16];
#pragma unroll
    for (int i = 0; i < 16; ++i) {
        v4i wv = wpipe[i & 7];
        if (i + 8 < 16) wpipe[i & 7] = *(const v4i*)(wb + (size_t)(i + 8) * KW);
        const int s0 = spread2(wv[0]), s1 = spread2(wv[1]);
        const int s2 = spread2(wv[2]), s3 = spread2(wv[3]);
        int bacc[16];
#pragma unroll
        for (int b = 0; b < 16; ++b) {
            int p = dot4(qr[b][0], s0, 0);
            p = dot4(qr[b][1], s1, p);
            p = dot4(qr[b][2], s2, p);
            bacc[b] = dot4(qr[b][3], s3, p);
        }
        // halving butterfly: 16 accs over 64 lanes (15 shuffles) + 2 k-folds
#define RST(S, N)                                                  \
        {                                                          \
            const bool up = (lane & S) != 0;                       \
            _Pragma("unroll") for (int ii = 0; ii < N; ++ii) {     \
                int snd = up ? bacc[ii] : bacc[ii + N];            \
                int kp  = up ? bacc[ii + N] : bacc[ii];            \
                bacc[ii] = kp + __shfl_xor(snd, S, 64);            \
            }                                                      \
        }
        RST(1, 8) RST(2, 4) RST(4, 2) RST(8, 1)
#undef RST
        int tot = bacc[0];
        tot += __shfl_xor(tot, 16, 64);
        tot += __shfl_xor(tot, 32, 64);
        acc2[i] = tot;   // lanes 0..15: partial for (b=a, row i, k-quarter wid)
    }

    // cross-wave reduce
#pragma unroll
    for (int i = 0; i < 16; ++i)
        if (lane < 16) red[wid][i][a] = acc2[i];
    __syncthreads();

    const int row = t & 15, b = t >> 4;   // consecutive t -> consecutive m (coalesced out)
    int sum = red[0][row][b] + red[1][row][b] + red[2][row][b] + red[3][row][b];
    const int sq = sumq_part[b * 4 + 0] + sumq_part[b * 4 + 1] +
                   sumq_part[b * 4 + 2] + sumq_part[b * 4 + 3];
    const float val = (float)(sum - sq) * invs[b] * wscale[m0 / GROUP_ROWS];
    out[(size_t)b * M_DIM + m0 + row] = val;
}

extern "C" void kernel_launch(void* const* d_in, const int* in_sizes, int n_in,
                              void* d_out, int out_size, void* d_ws, size_t ws_size,
                              hipStream_t stream) {
    const float* inp    = (const float*)d_in[0];
    const int*   wp     = (const int*)d_in[1];
    const float* wscale = (const float*)d_in[2];
    float* out = (float*)d_out;

    int*   qg   = (int*)d_ws;                  // 16384 words = 64 KB
    int*   sqp  = qg + B_DIM * KW;             // 64 ints
    float* invs = (float*)(sqp + B_DIM * 4);   // 16 floats

    quant_k<<<dim3(B_DIM * 4), dim3(256), 0, stream>>>(inp, qg, sqp, invs);
    gemm_k<<<dim3(NTILES), dim3(256), 0, stream>>>(wp, qg, sqp, invs, wscale, out);
}